// Round 10
// baseline (111.635 us; speedup 1.0000x reference)
//
#include <hip/hip_runtime.h>
#include <hip/hip_bf16.h>

// Problem constants
constexpr int BATCH = 4096;
constexpr int IN    = 512;
constexpr int OUT   = 512;
constexpr int ORD   = 8;
constexpr int NK    = ORD + 1;        // 9
constexpr float FA  = 1.0f, FB = 1.0f;

// GEMM inner dim EXCLUDES k=0 (J0 == 1 -> bias term), KP = 4096
constexpr int KP     = IN * ORD;
constexpr int KS_TOT = KP / 32;                // 128 k-steps total

typedef __attribute__((ext_vector_type(8))) short short8;   // 8 bf16
typedef __attribute__((ext_vector_type(4))) float floatx4;  // MFMA C/D

#define AS1 __attribute__((address_space(1)))
#define AS3 __attribute__((address_space(3)))

__device__ __forceinline__ float bf16bits_to_f32(short s) {
    union { unsigned int u; float f; } cv;
    cv.u = ((unsigned int)(unsigned short)s) << 16;
    return cv.f;
}
__device__ __forceinline__ short f32_to_bf16bits(float f) {
    __hip_bfloat16 h = __float2bfloat16(f);
    return *(short*)&h;
}

// ---------------------------------------------------------------------------
// Kernel 1 (fused prep): unchanged (control).
// ---------------------------------------------------------------------------
__global__ __launch_bounds__(256) void prep(const float* __restrict__ x,
                                            const float* __restrict__ w,
                                            const float* __restrict__ coeff,
                                            short* __restrict__ A2,
                                            short* __restrict__ B2,
                                            float* __restrict__ bias) {
    const int bid  = blockIdx.x;
    const int tid  = threadIdx.x;
    const int lane = tid & 63;
    const int quad = lane >> 4;
    const int l15  = lane & 15;

    if (bid < 1024) {
        const int mt  = bid >> 2;
        const int sub = ((bid & 3) << 2) + (tid >> 6);   // 0..15
        const int b   = mt * 16 + l15;
        const int i0  = sub * 32 + quad * 8;
        const float* xr = x + (size_t)b * IN + i0;
        float t[8];
#pragma unroll
        for (int e = 0; e < 8; ++e) {
            float xc = fminf(fmaxf(xr[e], -9.0f), 9.0f);
            float ex = __expf(2.0f * xc);
            t[e] = (ex - 1.0f) / (ex + 1.0f);
        }
        float pp[8], pc[8];
#pragma unroll
        for (int e = 0; e < 8; ++e) {
            pp[e] = 1.0f;
            pc[e] = 0.5f * (FA + FB + 2.0f) * t[e] - 0.5f * (FA - FB);
        }
        {
            short8 v;
#pragma unroll
            for (int e = 0; e < 8; ++e) v[e] = f32_to_bf16bits(pc[e]);
            *(short8*)(A2 + (((size_t)mt * KS_TOT + sub) * 64 + lane) * 8) = v;
        }
#pragma unroll
        for (int n = 2; n <= ORD; ++n) {
            float fn = (float)n;
            float k1 = (2.f*fn+FA+FB)*(2.f*fn+FA+FB-1.f) / (2.f*fn*(fn+FA+FB));
            float k2 = (2.f*fn+FA+FB-1.f)*(FA*FA-FB*FB) /
                       (2.f*fn*(fn+FA+FB)*(2.f*fn+FA+FB-2.f));
            float k3 = (fn+FA-1.f)*(fn+FB-1.f)*(2.f*fn+FA+FB) /
                       (fn*(fn+FA+FB)*(2.f*fn+FA+FB-2.f));
            short8 v;
#pragma unroll
            for (int e = 0; e < 8; ++e) {
                float nx = (k1*t[e] + k2)*pc[e] - k3*pp[e];
                pp[e] = pc[e]; pc[e] = nx;
                v[e] = f32_to_bf16bits(nx);
            }
            const int ks = (n - 1) * 16 + sub;
            *(short8*)(A2 + (((size_t)mt * KS_TOT + ks) * 64 + lane) * 8) = v;
        }
    } else if (bid < 1152) {
        const int b2  = bid - 1024;
        const int nt  = b2 >> 2;
        const int sub = ((b2 & 3) << 2) + (tid >> 6);
        const int o   = nt * 16 + l15;
        const int i0  = sub * 32 + quad * 8;
        const float* wr = w + (size_t)o * IN + i0;
        float wv[8];
#pragma unroll
        for (int e = 0; e < 8; ++e) wv[e] = wr[e];
        const float* cf = coeff + ((size_t)o * IN + i0) * NK;
#pragma unroll
        for (int n = 1; n <= ORD; ++n) {
            short8 v;
#pragma unroll
            for (int e = 0; e < 8; ++e)
                v[e] = f32_to_bf16bits(cf[(size_t)e * NK + n] * wv[e]);
            const int ks = (n - 1) * 16 + sub;
            *(short8*)(B2 + (((size_t)nt * KS_TOT + ks) * 64 + lane) * 8) = v;
        }
    } else {
        const int bb = bid - 1152;
        const int o  = bb * 4 + (tid >> 6);
        const float* cf = coeff + (size_t)o * IN * NK;
        const float* wr = w + (size_t)o * IN;
        float acc = 0.0f;
#pragma unroll
        for (int r = 0; r < IN / 64; ++r) {
            int i = r * 64 + lane;
            acc = fmaf(cf[(size_t)i * NK], wr[i], acc);
        }
#pragma unroll
        for (int off = 32; off >= 1; off >>= 1)
            acc += __shfl_xor(acc, off, 64);
        if (lane == 0) bias[o] = acc;
    }
}

// ---------------------------------------------------------------------------
// Kernel 2: FULL-K GEMM (v4). Split-K eliminated. (2nd resubmit; rounds 8-9
// benches never ran: GPUAcquisitionTimeout.)
//
// r18 post-mortem: v2 (wait choreography) and v3 (3 blocks/CU occupancy)
// both NEUTRAL (101-105 us) -> GEMM microstructure is not the lever; per-
// dispatch fixed costs + the P round-trip are. v4 collapses the pipeline:
// each block does the full K=4096 (64 iters x 2 k-steps), adds bias in the
// epilogue, writes float out directly. Removes reducek dispatch, one
// inter-kernel gap, and 33.6 MB of P HBM round-trip.
//
// Tile 128x64, grid (32,8) = 256 blocks = 1/CU. LDS 64 KB: 4 buffers x
// (2 k-steps x 8 m-lines x 1 KB), stage distance 3 (~2.5 iters of HBM
// latency budget). Per iter: BLOAD B(t+1) FIRST, then STAGE2(t+3) -- the
// compiler's B(t)-use wait then only forces stage(t+1) (1 iter early),
// never a fresh stage. End-of-iter vmcnt(12) leaves [st(t+2), B(t+1),
// st(t+3)] in flight and forces st(t+1) resident for the next iter's
// ds_reads. Linear id: id%8 = bx%8 -> all by-blocks of one bx share an
// XCD -> A-panel fetched once per XCD L2.
// ---------------------------------------------------------------------------
__global__ __launch_bounds__(256) void gemm_full(
        const short* __restrict__ A2,   // [256 mt][128 ks] x 1KB lines
        const short* __restrict__ B2,   // [32 nt][128 ks]  x 1KB lines
        const float* __restrict__ bias, // [512]
        float* __restrict__ out)        // [4096][512] f32
{
    // 4 buffers x 2 steps x 8 m-lines x 512 shorts = 64 KB
    __shared__ short sA[4 * 8192];

    const int tid  = threadIdx.x;
    const int lane = tid & 63;
    const int quad = lane >> 4;
    const int l15  = lane & 15;
    const int wave = tid >> 6;
    const int mw   = wave & 1;          // m half (64 rows)
    const int nw   = wave >> 1;         // n half (32 cols)
    const int bx = blockIdx.x;          // 0..31  (m-tiles of 128)
    const int by = blockIdx.y;          // 0..7   (n-tiles of 64)

    // B direct pointers: 2 n-frags per wave (nt = by*4 + nw*2 + j)
    const short* pb[2];
#pragma unroll
    for (int j = 0; j < 2; ++j)
        pb[j] = B2 + (((size_t)(by * 4 + nw * 2 + j) * KS_TOT) * 64 + lane) * 8;

    const int wv = wave;
    const short* aBase = A2 + ((size_t)(bx * 8) * KS_TOT) * 512;

    // Stage one 2-step batch (16 lines) into buffer BUF (literal).
    // Line ll = c*4+wv; mt = ll&7, s = ll>>3. Buffer layout [s][mt].
#define STAGE2(BT, BUF)                                                      \
    _Pragma("unroll")                                                        \
    for (int c = 0; c < 4; ++c) {                                            \
        const int ll = c * 4 + wv;                                           \
        const int mt = ll & 7;                                               \
        const int s  = ll >> 3;                                              \
        __builtin_amdgcn_global_load_lds(                                    \
            (const AS1 unsigned int*)(aBase +                                \
                ((size_t)mt * KS_TOT + (BT) * 2 + s) * 512 + lane * 8),      \
            (AS3 unsigned int*)(sA + (BUF) * 8192 + (c * 256 + tid) * 8),    \
            16, 0, 0);                                                       \
    }

    // Load k-pair (K0, K0+1) into slot pair (S0, S1): 4 global loads.
#define BLOAD(S0, S1, K0)                                                    \
    _Pragma("unroll")                                                        \
    for (int j = 0; j < 2; ++j) {                                            \
        S0[j] = *(const short8*)(pb[j] + (size_t)(K0) * 512);                \
        S1[j] = *(const short8*)(pb[j] + (size_t)((K0) + 1) * 512);          \
    }

    floatx4 acc[4][2];
#pragma unroll
    for (int i = 0; i < 4; ++i)
#pragma unroll
        for (int j = 0; j < 2; ++j) acc[i][j] = (floatx4)0.0f;

#define ASTEP(BUFI, S, BSLOT)                                                \
    {                                                                        \
        short8 af[4];                                                        \
        _Pragma("unroll")                                                    \
        for (int i = 0; i < 4; ++i)                                          \
            af[i] = *(const short8*)(sA + (BUFI) * 8192 +                    \
                        (((S) * 8 + mw * 4 + i) * 64 + lane) * 8);           \
        __builtin_amdgcn_s_setprio(1);                                       \
        _Pragma("unroll")                                                    \
        for (int i = 0; i < 4; ++i)                                          \
            _Pragma("unroll")                                                \
            for (int j = 0; j < 2; ++j)                                      \
                acc[i][j] = __builtin_amdgcn_mfma_f32_16x16x32_bf16(         \
                                af[i], BSLOT[j], acc[i][j], 0, 0, 0);        \
        __builtin_amdgcn_s_setprio(0);                                       \
    }

    short8 bsA0[2], bsA1[2], bsB0[2], bsB1[2];

    // Prologue: stage batches 0..2; B k=0,1 into set A. Issue order puts
    // B0 right after st0 so the iter-0 B0-use wait forces only st0.
    STAGE2(0, 0)
    BLOAD(bsA0, bsA1, 0)
    STAGE2(1, 1)
    STAGE2(2, 2)
    // FIFO: [st0(4)][B0(4)][st1(4)][st2(4)] -> vmcnt(12) forces st0 only.
    asm volatile("s_waitcnt vmcnt(12)" ::: "memory");
    __builtin_amdgcn_s_barrier();

    // One iteration: consume batch T (k=2T,2T+1) from buf BUFI with slots
    // C0/C1; load B for T+1 into L0/L1; stage batch T+3 into SBUF.
#define ITERX(T, BUFI, SBUF, C0, C1, L0, L1)                                 \
    BLOAD(L0, L1, 2 * (T) + 2)                                               \
    STAGE2((T) + 3, SBUF)                                                    \
    ASTEP(BUFI, 0, C0) ASTEP(BUFI, 1, C1)                                    \
    asm volatile("s_waitcnt vmcnt(12)" ::: "memory");                        \
    __builtin_amdgcn_s_barrier();

    // Steady state: t = 0..59 in groups of 4 (buffer cycle period).
    for (int q = 0; q < 15; ++q) {
        const int t0 = q * 4;
        ITERX(t0,     0, 3, bsA0, bsA1, bsB0, bsB1)
        ITERX(t0 + 1, 1, 0, bsB0, bsB1, bsA0, bsA1)
        ITERX(t0 + 2, 2, 1, bsA0, bsA1, bsB0, bsB1)
        ITERX(t0 + 3, 3, 2, bsB0, bsB1, bsA0, bsA1)
    }
    // t = 60: last stage (batch 63 -> buf 3).
    ITERX(60, 0, 3, bsA0, bsA1, bsB0, bsB1)
    // t = 61: no stage. Consume B (loaded t=60); load A k=124,125.
    BLOAD(bsA0, bsA1, 124)
    ASTEP(1, 0, bsB0) ASTEP(1, 1, bsB1)
    // Outstanding after B61-use wait: [st63(4), B62(4)] = 8.
    asm volatile("s_waitcnt vmcnt(8)" ::: "memory");
    __builtin_amdgcn_s_barrier();
    // t = 62: consume A; load B k=126,127.
    BLOAD(bsB0, bsB1, 126)
    ASTEP(2, 0, bsA0) ASTEP(2, 1, bsA1)
    asm volatile("s_waitcnt vmcnt(4)" ::: "memory");
    __builtin_amdgcn_s_barrier();
    // t = 63: consume B from buf 3.
    ASTEP(3, 0, bsB0) ASTEP(3, 1, bsB1)

#undef ITERX
#undef ASTEP
#undef BLOAD
#undef STAGE2

    // Epilogue: C/D layout col = lane&15, row = quad*4 + reg.
    // out[b,o] = acc + bias[o], float, direct.
    const int m0 = bx * 128, n0 = by * 64;
    float bj[2];
#pragma unroll
    for (int j = 0; j < 2; ++j) bj[j] = bias[n0 + nw * 32 + j * 16 + l15];
#pragma unroll
    for (int i = 0; i < 4; ++i) {
        const int r0 = m0 + mw * 64 + i * 16 + quad * 4;
#pragma unroll
        for (int j = 0; j < 2; ++j) {
            const int c = n0 + nw * 32 + j * 16 + l15;
#pragma unroll
            for (int r = 0; r < 4; ++r)
                out[(size_t)(r0 + r) * OUT + c] = acc[i][j][r] + bj[j];
        }
    }
}

// ---------------------------------------------------------------------------
extern "C" void kernel_launch(void* const* d_in, const int* in_sizes, int n_in,
                              void* d_out, int out_size, void* d_ws, size_t ws_size,
                              hipStream_t stream) {
    const float* x     = (const float*)d_in[0];   // [4096,512]
    const float* w     = (const float*)d_in[1];   // [512,512]
    const float* coeff = (const float*)d_in[2];   // [512,512,9]
    float* out = (float*)d_out;                   // [4096,512]

    // workspace layout (bytes)
    char* ws = (char*)d_ws;
    short* A2 = (short*)ws;                                  // 33,554,432 B
    char* p1c = ws + (size_t)BATCH * KP * 2;
    short* B2 = (short*)p1c;                                 //  4,194,304 B
    float* bias = (float*)(p1c + (size_t)OUT * KP * 2);      //      2,048 B

    prep<<<1280, 256, 0, stream>>>(x, w, coeff, A2, B2, bias);
    gemm_full<<<dim3(32, 8), 256, 0, stream>>>(A2, B2, bias, out);
}

// Round 13
// 109.068 us; speedup vs baseline: 1.0235x; 1.0235x over previous
//
#include <hip/hip_runtime.h>
#include <hip/hip_bf16.h>

// Problem constants
constexpr int BATCH = 4096;
constexpr int IN    = 512;
constexpr int OUT   = 512;
constexpr int ORD   = 8;
constexpr int NK    = ORD + 1;        // 9
constexpr float FA  = 1.0f, FB = 1.0f;

// GEMM inner dim EXCLUDES k=0 (J0 == 1 -> bias term), KP = 4096
constexpr int KP     = IN * ORD;
constexpr int KS_TOT = KP / 32;                // 128 k-steps total

typedef __attribute__((ext_vector_type(8))) short short8;   // 8 bf16
typedef __attribute__((ext_vector_type(4))) float floatx4;  // MFMA C/D

#define AS1 __attribute__((address_space(1)))
#define AS3 __attribute__((address_space(3)))

__device__ __forceinline__ float bf16bits_to_f32(short s) {
    union { unsigned int u; float f; } cv;
    cv.u = ((unsigned int)(unsigned short)s) << 16;
    return cv.f;
}
__device__ __forceinline__ short f32_to_bf16bits(float f) {
    __hip_bfloat16 h = __float2bfloat16(f);
    return *(short*)&h;
}

// ---------------------------------------------------------------------------
// Kernel 1 (fused prep): unchanged (control).
// ---------------------------------------------------------------------------
__global__ __launch_bounds__(256) void prep(const float* __restrict__ x,
                                            const float* __restrict__ w,
                                            const float* __restrict__ coeff,
                                            short* __restrict__ A2,
                                            short* __restrict__ B2,
                                            float* __restrict__ bias) {
    const int bid  = blockIdx.x;
    const int tid  = threadIdx.x;
    const int lane = tid & 63;
    const int quad = lane >> 4;
    const int l15  = lane & 15;

    if (bid < 1024) {
        const int mt  = bid >> 2;
        const int sub = ((bid & 3) << 2) + (tid >> 6);   // 0..15
        const int b   = mt * 16 + l15;
        const int i0  = sub * 32 + quad * 8;
        const float* xr = x + (size_t)b * IN + i0;
        float t[8];
#pragma unroll
        for (int e = 0; e < 8; ++e) {
            float xc = fminf(fmaxf(xr[e], -9.0f), 9.0f);
            float ex = __expf(2.0f * xc);
            t[e] = (ex - 1.0f) / (ex + 1.0f);
        }
        float pp[8], pc[8];
#pragma unroll
        for (int e = 0; e < 8; ++e) {
            pp[e] = 1.0f;
            pc[e] = 0.5f * (FA + FB + 2.0f) * t[e] - 0.5f * (FA - FB);
        }
        {
            short8 v;
#pragma unroll
            for (int e = 0; e < 8; ++e) v[e] = f32_to_bf16bits(pc[e]);
            *(short8*)(A2 + (((size_t)mt * KS_TOT + sub) * 64 + lane) * 8) = v;
        }
#pragma unroll
        for (int n = 2; n <= ORD; ++n) {
            float fn = (float)n;
            float k1 = (2.f*fn+FA+FB)*(2.f*fn+FA+FB-1.f) / (2.f*fn*(fn+FA+FB));
            float k2 = (2.f*fn+FA+FB-1.f)*(FA*FA-FB*FB) /
                       (2.f*fn*(fn+FA+FB)*(2.f*fn+FA+FB-2.f));
            float k3 = (fn+FA-1.f)*(fn+FB-1.f)*(2.f*fn+FA+FB) /
                       (fn*(fn+FA+FB)*(2.f*fn+FA+FB-2.f));
            short8 v;
#pragma unroll
            for (int e = 0; e < 8; ++e) {
                float nx = (k1*t[e] + k2)*pc[e] - k3*pp[e];
                pp[e] = pc[e]; pc[e] = nx;
                v[e] = f32_to_bf16bits(nx);
            }
            const int ks = (n - 1) * 16 + sub;
            *(short8*)(A2 + (((size_t)mt * KS_TOT + ks) * 64 + lane) * 8) = v;
        }
    } else if (bid < 1152) {
        const int b2  = bid - 1024;
        const int nt  = b2 >> 2;
        const int sub = ((b2 & 3) << 2) + (tid >> 6);
        const int o   = nt * 16 + l15;
        const int i0  = sub * 32 + quad * 8;
        const float* wr = w + (size_t)o * IN + i0;
        float wv[8];
#pragma unroll
        for (int e = 0; e < 8; ++e) wv[e] = wr[e];
        const float* cf = coeff + ((size_t)o * IN + i0) * NK;
#pragma unroll
        for (int n = 1; n <= ORD; ++n) {
            short8 v;
#pragma unroll
            for (int e = 0; e < 8; ++e)
                v[e] = f32_to_bf16bits(cf[(size_t)e * NK + n] * wv[e]);
            const int ks = (n - 1) * 16 + sub;
            *(short8*)(B2 + (((size_t)nt * KS_TOT + ks) * 64 + lane) * 8) = v;
        }
    } else {
        const int bb = bid - 1152;
        const int o  = bb * 4 + (tid >> 6);
        const float* cf = coeff + (size_t)o * IN * NK;
        const float* wr = w + (size_t)o * IN;
        float acc = 0.0f;
#pragma unroll
        for (int r = 0; r < IN / 64; ++r) {
            int i = r * 64 + lane;
            acc = fmaf(cf[(size_t)i * NK], wr[i], acc);
        }
#pragma unroll
        for (int off = 32; off >= 1; off >>= 1)
            acc += __shfl_xor(acc, off, 64);
        if (lane == 0) bias[o] = acc;
    }
}

// ---------------------------------------------------------------------------
// Kernel 2: FULL-K GEMM v5 — fusion kept, occupancy restored. (2nd resubmit;
// rounds 11-12 benches never ran: GPUAcquisitionTimeout.)
//
// r20 post-mortem (normalized by fill-dispatch time, clocks drift):
// v2 2.43x, v3 2.44x, v4 2.52x -> v4's fusion (no reducek/P) was masked by
// a ~15us gemm regression. Cause: grid=256 = 1 block/CU, zero co-resident
// overlap -> every vmcnt/barrier stall exposed. v2/v3 always had >=2.
//
// v5: tile 128x32, grid (32,16) = 512 blocks = 2/CU (launch_bounds(256,2)).
// LDS 48KB = 3 buffers x 16KB (2-kstep batches), stage distance 2 + a
// co-resident block for latency. Per wave: 4 m-frags x 1 n-frag (acc 16
// VGPR); B 1 frag/kstep via L1, loaded 1 iter ahead into alternate reg set.
// Per-CU traffic identical to v4 (B 16KB/iter, A 16KB/iter staged).
// End-of-iter vmcnt(10): leaves [st(t+2)(8), B(2)] in flight, forces
// st(t+1) resident. id%8 = bx%8 -> A-panel XCD L2 locality.
// ---------------------------------------------------------------------------
__global__ __launch_bounds__(256, 2) void gemm_full(
        const short* __restrict__ A2,   // [256 mt][128 ks] x 1KB lines
        const short* __restrict__ B2,   // [32 nt][128 ks]  x 1KB lines
        const float* __restrict__ bias, // [512]
        float* __restrict__ out)        // [4096][512] f32
{
    // 3 buffers x 2 ksteps x 8 m-lines x 512 shorts = 48 KB
    __shared__ short sA[3 * 8192];

    const int tid  = threadIdx.x;
    const int lane = tid & 63;
    const int quad = lane >> 4;
    const int l15  = lane & 15;
    const int wave = tid >> 6;
    const int mw   = wave & 1;          // m half (64 rows)
    const int nw   = wave >> 1;         // n half (16 cols)
    const int bx = blockIdx.x;          // 0..31  (m-tiles of 128)
    const int by = blockIdx.y;          // 0..15  (n-tiles of 32)

    // B pointer: 1 n-frag per wave (nt = by*2 + nw)
    const short* pb = B2 + ((size_t)(by * 2 + nw) * KS_TOT * 64 + lane) * 8;

    const int wv = wave;
    const short* aBase = A2 + ((size_t)(bx * 8) * KS_TOT) * 512;

    // Stage one 2-kstep batch (16 lines of 1KB) into buffer BUF.
    // Line ll = c*4+wv; mt = ll&7, s = ll>>3. Buffer layout [s][mt].
#define STAGE2(BT, BUF)                                                      \
    _Pragma("unroll")                                                        \
    for (int c = 0; c < 4; ++c) {                                            \
        const int ll = c * 4 + wv;                                           \
        const int mt = ll & 7;                                               \
        const int s  = ll >> 3;                                              \
        __builtin_amdgcn_global_load_lds(                                    \
            (const AS1 unsigned int*)(aBase +                                \
                ((size_t)mt * KS_TOT + (BT) * 2 + s) * 512 + lane * 8),      \
            (AS3 unsigned int*)(sA + (BUF) * 8192 + (c * 256 + tid) * 8),    \
            16, 0, 0);                                                       \
    }

    // Load k-pair (K0, K0+1): 2 global loads (one frag each kstep).
#define BLOAD(S0, S1, K0)                                                    \
    {                                                                        \
        S0 = *(const short8*)(pb + (size_t)(K0) * 512);                      \
        S1 = *(const short8*)(pb + (size_t)((K0) + 1) * 512);                \
    }

    floatx4 acc[4];
#pragma unroll
    for (int i = 0; i < 4; ++i) acc[i] = (floatx4)0.0f;

#define ASTEP(BUFI, S, BSLOT)                                                \
    {                                                                        \
        short8 af[4];                                                        \
        _Pragma("unroll")                                                    \
        for (int i = 0; i < 4; ++i)                                          \
            af[i] = *(const short8*)(sA + (BUFI) * 8192 +                    \
                        (((S) * 8 + mw * 4 + i) * 64 + lane) * 8);           \
        __builtin_amdgcn_s_setprio(1);                                       \
        _Pragma("unroll")                                                    \
        for (int i = 0; i < 4; ++i)                                          \
            acc[i] = __builtin_amdgcn_mfma_f32_16x16x32_bf16(                \
                         af[i], BSLOT, acc[i], 0, 0, 0);                     \
        __builtin_amdgcn_s_setprio(0);                                       \
    }

    short8 bsA0, bsA1, bsB0, bsB1;

    // Prologue: stage batches 0,1; B k=0,1 into set A.
    STAGE2(0, 0)
    STAGE2(1, 1)
    BLOAD(bsA0, bsA1, 0)
    // FIFO: [st0(8)][st1(8)][B(2)] -> vmcnt(10) forces st0 only.
    asm volatile("s_waitcnt vmcnt(10)" ::: "memory");
    __builtin_amdgcn_s_barrier();

    // Iter t: consume batch t (k=2t,2t+1) from buf t%3 with set C; stage
    // batch t+2 into buf (t+2)%3; load B k=2t+2 into the other set.
#define ITERX(T, BUF, SBUF, C0, C1, N0, N1)                                  \
    STAGE2((T) + 2, SBUF)                                                    \
    BLOAD(N0, N1, 2 * (T) + 2)                                               \
    ASTEP(BUF, 0, C0) ASTEP(BUF, 1, C1)                                      \
    asm volatile("s_waitcnt vmcnt(10)" ::: "memory");                        \
    __builtin_amdgcn_s_barrier();

    // Steady state: t = 0..59 in groups of 6 (lcm of 3 buffers, 2 sets).
    for (int g = 0; g < 10; ++g) {
        const int t0 = g * 6;
        ITERX(t0,     0, 2, bsA0, bsA1, bsB0, bsB1)
        ITERX(t0 + 1, 1, 0, bsB0, bsB1, bsA0, bsA1)
        ITERX(t0 + 2, 2, 1, bsA0, bsA1, bsB0, bsB1)
        ITERX(t0 + 3, 0, 2, bsB0, bsB1, bsA0, bsA1)
        ITERX(t0 + 4, 1, 0, bsA0, bsA1, bsB0, bsB1)
        ITERX(t0 + 5, 2, 1, bsB0, bsB1, bsA0, bsA1)
    }
    // t = 60 (even: consume A, load B), t = 61 (stage batch 63 -> buf 0).
    ITERX(60, 0, 2, bsA0, bsA1, bsB0, bsB1)
    ITERX(61, 1, 0, bsB0, bsB1, bsA0, bsA1)
    // t = 62: consume A from buf 2; load last B pair; no stage.
    BLOAD(bsB0, bsB1, 126)
    ASTEP(2, 0, bsA0) ASTEP(2, 1, bsA1)
    // In flight: [st63(8) from t=61, B(2)] -> vmcnt(2) forces st63.
    asm volatile("s_waitcnt vmcnt(2)" ::: "memory");
    __builtin_amdgcn_s_barrier();
    // t = 63: consume B from buf 0.
    ASTEP(0, 0, bsB0) ASTEP(0, 1, bsB1)

#undef ITERX
#undef ASTEP
#undef BLOAD
#undef STAGE2

    // Epilogue: C/D layout col = lane&15, row = quad*4 + reg.
    // out[b,o] = acc + bias[o], float, direct.
    const int m0 = bx * 128, n0 = by * 32;
    const int c  = n0 + nw * 16 + l15;
    const float bj = bias[c];
#pragma unroll
    for (int i = 0; i < 4; ++i) {
        const int r0 = m0 + mw * 64 + i * 16 + quad * 4;
#pragma unroll
        for (int r = 0; r < 4; ++r)
            out[(size_t)(r0 + r) * OUT + c] = acc[i][r] + bj;
    }
}

// ---------------------------------------------------------------------------
extern "C" void kernel_launch(void* const* d_in, const int* in_sizes, int n_in,
                              void* d_out, int out_size, void* d_ws, size_t ws_size,
                              hipStream_t stream) {
    const float* x     = (const float*)d_in[0];   // [4096,512]
    const float* w     = (const float*)d_in[1];   // [512,512]
    const float* coeff = (const float*)d_in[2];   // [512,512,9]
    float* out = (float*)d_out;                   // [4096,512]

    // workspace layout (bytes)
    char* ws = (char*)d_ws;
    short* A2 = (short*)ws;                                  // 33,554,432 B
    char* p1c = ws + (size_t)BATCH * KP * 2;
    short* B2 = (short*)p1c;                                 //  4,194,304 B
    float* bias = (float*)(p1c + (size_t)OUT * KP * 2);      //      2,048 B

    prep<<<1280, 256, 0, stream>>>(x, w, coeff, A2, B2, bias);
    gemm_full<<<dim3(32, 16), 256, 0, stream>>>(A2, B2, bias, out);
}

// Round 19
// 107.831 us; speedup vs baseline: 1.0353x; 1.0115x over previous
//
#include <hip/hip_runtime.h>
#include <hip/hip_bf16.h>

// Problem constants
constexpr int BATCH = 4096;
constexpr int IN    = 512;
constexpr int OUT   = 512;
constexpr int ORD   = 8;
constexpr int NK    = ORD + 1;        // 9
constexpr float FA  = 1.0f, FB = 1.0f;

// GEMM inner dim EXCLUDES k=0 (J0 == 1 -> bias term), KP = 4096
constexpr int KP     = IN * ORD;
constexpr int KS_TOT = KP / 32;                // 128 k-steps total

typedef __attribute__((ext_vector_type(8))) short short8;   // 8 bf16
typedef __attribute__((ext_vector_type(4))) float floatx4;  // MFMA C/D

#define AS1 __attribute__((address_space(1)))
#define AS3 __attribute__((address_space(3)))

__device__ __forceinline__ float bf16bits_to_f32(short s) {
    union { unsigned int u; float f; } cv;
    cv.u = ((unsigned int)(unsigned short)s) << 16;
    return cv.f;
}
__device__ __forceinline__ short f32_to_bf16bits(float f) {
    __hip_bfloat16 h = __float2bfloat16(f);
    return *(short*)&h;
}

// ---------------------------------------------------------------------------
// Kernel 1 (fused prep): unchanged (control).
// ---------------------------------------------------------------------------
__global__ __launch_bounds__(256) void prep(const float* __restrict__ x,
                                            const float* __restrict__ w,
                                            const float* __restrict__ coeff,
                                            short* __restrict__ A2,
                                            short* __restrict__ B2,
                                            float* __restrict__ bias) {
    const int bid  = blockIdx.x;
    const int tid  = threadIdx.x;
    const int lane = tid & 63;
    const int quad = lane >> 4;
    const int l15  = lane & 15;

    if (bid < 1024) {
        const int mt  = bid >> 2;
        const int sub = ((bid & 3) << 2) + (tid >> 6);   // 0..15
        const int b   = mt * 16 + l15;
        const int i0  = sub * 32 + quad * 8;
        const float* xr = x + (size_t)b * IN + i0;
        float t[8];
#pragma unroll
        for (int e = 0; e < 8; ++e) {
            float xc = fminf(fmaxf(xr[e], -9.0f), 9.0f);
            float ex = __expf(2.0f * xc);
            t[e] = (ex - 1.0f) / (ex + 1.0f);
        }
        float pp[8], pc[8];
#pragma unroll
        for (int e = 0; e < 8; ++e) {
            pp[e] = 1.0f;
            pc[e] = 0.5f * (FA + FB + 2.0f) * t[e] - 0.5f * (FA - FB);
        }
        {
            short8 v;
#pragma unroll
            for (int e = 0; e < 8; ++e) v[e] = f32_to_bf16bits(pc[e]);
            *(short8*)(A2 + (((size_t)mt * KS_TOT + sub) * 64 + lane) * 8) = v;
        }
#pragma unroll
        for (int n = 2; n <= ORD; ++n) {
            float fn = (float)n;
            float k1 = (2.f*fn+FA+FB)*(2.f*fn+FA+FB-1.f) / (2.f*fn*(fn+FA+FB));
            float k2 = (2.f*fn+FA+FB-1.f)*(FA*FA-FB*FB) /
                       (2.f*fn*(fn+FA+FB)*(2.f*fn+FA+FB-2.f));
            float k3 = (fn+FA-1.f)*(fn+FB-1.f)*(2.f*fn+FA+FB) /
                       (fn*(fn+FA+FB)*(2.f*fn+FA+FB-2.f));
            short8 v;
#pragma unroll
            for (int e = 0; e < 8; ++e) {
                float nx = (k1*t[e] + k2)*pc[e] - k3*pp[e];
                pp[e] = pc[e]; pc[e] = nx;
                v[e] = f32_to_bf16bits(nx);
            }
            const int ks = (n - 1) * 16 + sub;
            *(short8*)(A2 + (((size_t)mt * KS_TOT + ks) * 64 + lane) * 8) = v;
        }
    } else if (bid < 1152) {
        const int b2  = bid - 1024;
        const int nt  = b2 >> 2;
        const int sub = ((b2 & 3) << 2) + (tid >> 6);
        const int o   = nt * 16 + l15;
        const int i0  = sub * 32 + quad * 8;
        const float* wr = w + (size_t)o * IN + i0;
        float wv[8];
#pragma unroll
        for (int e = 0; e < 8; ++e) wv[e] = wr[e];
        const float* cf = coeff + ((size_t)o * IN + i0) * NK;
#pragma unroll
        for (int n = 1; n <= ORD; ++n) {
            short8 v;
#pragma unroll
            for (int e = 0; e < 8; ++e)
                v[e] = f32_to_bf16bits(cf[(size_t)e * NK + n] * wv[e]);
            const int ks = (n - 1) * 16 + sub;
            *(short8*)(B2 + (((size_t)nt * KS_TOT + ks) * 64 + lane) * 8) = v;
        }
    } else {
        const int bb = bid - 1152;
        const int o  = bb * 4 + (tid >> 6);
        const float* cf = coeff + (size_t)o * IN * NK;
        const float* wr = w + (size_t)o * IN;
        float acc = 0.0f;
#pragma unroll
        for (int r = 0; r < IN / 64; ++r) {
            int i = r * 64 + lane;
            acc = fmaf(cf[(size_t)i * NK], wr[i], acc);
        }
#pragma unroll
        for (int off = 32; off >= 1; off >>= 1)
            acc += __shfl_xor(acc, off, 64);
        if (lane == 0) bias[o] = acc;
    }
}

// ---------------------------------------------------------------------------
// Kernel 2: FULL-K GEMM v6 — 64x64 tile (LDS-read dedup). (5th resubmit;
// rounds 14-18 benches never ran: GPUAcquisitionTimeout.)
//
// r23 post-mortem (fill-normalized): v2 2.43x, v3 2.44x, v4 2.52x, v5 2.33x.
// v5's fusion + 2 blocks/CU is the best structure so far. Per-CU-iter pipe
// model of v5: A ds_reads 64 x b128 x 12cyc = 768 cyc (each A-frag read by
// BOTH nw-waves), B-L1 250 cyc, MFMA 160 cyc -> LDS pipe dominates.
//
// v6: tile 64x64, waves 2m x 2n, each wave 2 m-frags x 2 n-frags (acc 16
// VGPR). A-read redundancy per output cell halves: LDS 384 cyc/CU-iter;
// B-L1 doubles to 500 cyc -> max pipe 768 -> ~500 (-35%). Grid (64,8) =
// 512 blocks = 2/CU. LDS 24 KB = 3 bufs x 8 KB (2-kstep batches), stage
// distance 2. Per iter: BLOAD(4) then STAGE2(2); end-of-iter vmcnt(6)
// leaves [B(4), st(2)] in flight, forces last iter's stage (FIFO-older).
// id%8 = bx%8 -> A-panel XCD L2 locality; B2 (4MB) fits per-XCD L2.
// ---------------------------------------------------------------------------
__global__ __launch_bounds__(256, 2) void gemm_full(
        const short* __restrict__ A2,   // [256 mt][128 ks] x 1KB lines
        const short* __restrict__ B2,   // [32 nt][128 ks]  x 1KB lines
        const float* __restrict__ bias, // [512]
        float* __restrict__ out)        // [4096][512] f32
{
    // 3 buffers x 2 ksteps x 4 m-lines x 512 shorts = 24 KB
    __shared__ short sA[3 * 4096];

    const int tid  = threadIdx.x;
    const int lane = tid & 63;
    const int quad = lane >> 4;
    const int l15  = lane & 15;
    const int wave = tid >> 6;
    const int mw   = wave & 1;          // m half (32 rows)
    const int nw   = wave >> 1;         // n half (32 cols)
    const int bx = blockIdx.x;          // 0..63  (m-tiles of 64)
    const int by = blockIdx.y;          // 0..7   (n-tiles of 64)

    // B pointers: 2 n-frags per wave (nt = by*4 + nw*2 + j)
    const short* pb[2];
#pragma unroll
    for (int j = 0; j < 2; ++j)
        pb[j] = B2 + (((size_t)(by * 4 + nw * 2 + j) * KS_TOT) * 64 + lane) * 8;

    const int wv = wave;
    const short* aBase = A2 + ((size_t)(bx * 4) * KS_TOT) * 512;

    // Stage one 2-kstep batch (8 lines of 1KB) into buffer BUF.
    // Line ll = c*4+wv; mt = ll&3, s = ll>>2. Buffer layout [s][mt].
#define STAGE2(BT, BUF)                                                      \
    _Pragma("unroll")                                                        \
    for (int c = 0; c < 2; ++c) {                                            \
        const int ll = c * 4 + wv;                                           \
        const int mt = ll & 3;                                               \
        const int s  = ll >> 2;                                              \
        __builtin_amdgcn_global_load_lds(                                    \
            (const AS1 unsigned int*)(aBase +                                \
                ((size_t)mt * KS_TOT + (BT) * 2 + s) * 512 + lane * 8),      \
            (AS3 unsigned int*)(sA + (BUF) * 4096 + (c * 256 + tid) * 8),    \
            16, 0, 0);                                                       \
    }

    // Load k-pair (K0, K0+1) into frag-pair arrays: 4 global loads.
#define BLOAD(S0, S1, K0)                                                    \
    _Pragma("unroll")                                                        \
    for (int j = 0; j < 2; ++j) {                                            \
        S0[j] = *(const short8*)(pb[j] + (size_t)(K0) * 512);                \
        S1[j] = *(const short8*)(pb[j] + (size_t)((K0) + 1) * 512);          \
    }

    floatx4 acc[2][2];
#pragma unroll
    for (int i = 0; i < 2; ++i)
#pragma unroll
        for (int j = 0; j < 2; ++j) acc[i][j] = (floatx4)0.0f;

#define ASTEP(BUFI, S, BS)                                                   \
    {                                                                        \
        short8 af[2];                                                        \
        _Pragma("unroll")                                                    \
        for (int i = 0; i < 2; ++i)                                          \
            af[i] = *(const short8*)(sA + (BUFI) * 4096 +                    \
                        (((S) * 4 + mw * 2 + i) * 64 + lane) * 8);           \
        __builtin_amdgcn_s_setprio(1);                                       \
        _Pragma("unroll")                                                    \
        for (int i = 0; i < 2; ++i)                                          \
            _Pragma("unroll")                                                \
            for (int j = 0; j < 2; ++j)                                      \
                acc[i][j] = __builtin_amdgcn_mfma_f32_16x16x32_bf16(         \
                                af[i], BS[j], acc[i][j], 0, 0, 0);           \
        __builtin_amdgcn_s_setprio(0);                                       \
    }

    short8 bsA0[2], bsA1[2], bsB0[2], bsB1[2];

    // Prologue: stage batches 0,1; B k=0,1 into set A.
    STAGE2(0, 0)
    STAGE2(1, 1)
    BLOAD(bsA0, bsA1, 0)
    // FIFO: [st0(2)][st1(2)][B(4)] -> vmcnt(6) forces st0 only.
    asm volatile("s_waitcnt vmcnt(6)" ::: "memory");
    __builtin_amdgcn_s_barrier();

    // Iter t: consume batch t (k=2t,2t+1) from buf t%3 with set C; load B
    // k=2t+2 into the other set; stage batch t+2 into buf (t+2)%3.
#define ITERX(T, BUF, SBUF, C0, C1, N0, N1)                                  \
    BLOAD(N0, N1, 2 * (T) + 2)                                               \
    STAGE2((T) + 2, SBUF)                                                    \
    ASTEP(BUF, 0, C0) ASTEP(BUF, 1, C1)                                      \
    asm volatile("s_waitcnt vmcnt(6)" ::: "memory");                         \
    __builtin_amdgcn_s_barrier();

    // Steady state: t = 0..59 in groups of 6 (lcm of 3 buffers, 2 sets).
    for (int g = 0; g < 10; ++g) {
        const int t0 = g * 6;
        ITERX(t0,     0, 2, bsA0, bsA1, bsB0, bsB1)
        ITERX(t0 + 1, 1, 0, bsB0, bsB1, bsA0, bsA1)
        ITERX(t0 + 2, 2, 1, bsA0, bsA1, bsB0, bsB1)
        ITERX(t0 + 3, 0, 2, bsB0, bsB1, bsA0, bsA1)
        ITERX(t0 + 4, 1, 0, bsA0, bsA1, bsB0, bsB1)
        ITERX(t0 + 5, 2, 1, bsB0, bsB1, bsA0, bsA1)
    }
    // t = 60 (consume A, stage 62), t = 61 (consume B, stage 63 -> buf 0).
    ITERX(60, 0, 2, bsA0, bsA1, bsB0, bsB1)
    ITERX(61, 1, 0, bsB0, bsB1, bsA0, bsA1)
    // t = 62: consume A from buf 2; load last B pair; no stage.
    BLOAD(bsB0, bsB1, 126)
    ASTEP(2, 0, bsA0) ASTEP(2, 1, bsA1)
    // In flight: [st63(2) from t=61, B(4)] -> vmcnt(4) forces st63.
    asm volatile("s_waitcnt vmcnt(4)" ::: "memory");
    __builtin_amdgcn_s_barrier();
    // t = 63: consume B from buf 0.
    ASTEP(0, 0, bsB0) ASTEP(0, 1, bsB1)

#undef ITERX
#undef ASTEP
#undef BLOAD
#undef STAGE2

    // Epilogue: C/D layout col = lane&15, row = quad*4 + reg.
    // out[b,o] = acc + bias[o], float, direct.
    const int m0 = bx * 64, n0 = by * 64;
    float bj[2];
#pragma unroll
    for (int j = 0; j < 2; ++j) bj[j] = bias[n0 + nw * 32 + j * 16 + l15];
#pragma unroll
    for (int i = 0; i < 2; ++i) {
        const int r0 = m0 + mw * 32 + i * 16 + quad * 4;
#pragma unroll
        for (int j = 0; j < 2; ++j) {
            const int c = n0 + nw * 32 + j * 16 + l15;
#pragma unroll
            for (int r = 0; r < 4; ++r)
                out[(size_t)(r0 + r) * OUT + c] = acc[i][j][r] + bj[j];
        }
    }
}

// ---------------------------------------------------------------------------
extern "C" void kernel_launch(void* const* d_in, const int* in_sizes, int n_in,
                              void* d_out, int out_size, void* d_ws, size_t ws_size,
                              hipStream_t stream) {
    const float* x     = (const float*)d_in[0];   // [4096,512]
    const float* w     = (const float*)d_in[1];   // [512,512]
    const float* coeff = (const float*)d_in[2];   // [512,512,9]
    float* out = (float*)d_out;                   // [4096,512]

    // workspace layout (bytes)
    char* ws = (char*)d_ws;
    short* A2 = (short*)ws;                                  // 33,554,432 B
    char* p1c = ws + (size_t)BATCH * KP * 2;
    short* B2 = (short*)p1c;                                 //  4,194,304 B
    float* bias = (float*)(p1c + (size_t)OUT * KP * 2);      //      2,048 B

    prep<<<1280, 256, 0, stream>>>(x, w, coeff, A2, B2, bias);
    gemm_full<<<dim3(64, 8), 256, 0, stream>>>(A2, B2, bias, out);
}